// Round 4
// baseline (573.338 us; speedup 1.0000x reference)
//
#include <hip/hip_runtime.h>
#include <hip/hip_bf16.h>
#include <cmath>

typedef __attribute__((ext_vector_type(8))) short bf16x8;
typedef __attribute__((ext_vector_type(4))) float f32x4;

__device__ __forceinline__ float bf2f(unsigned short u) {
    unsigned int x = ((unsigned int)u) << 16;
    return __builtin_bit_cast(float, x);
}
__device__ __forceinline__ unsigned short f2bf(float f) {
    unsigned int x = __builtin_bit_cast(unsigned int, f);
    unsigned int lsb = (x >> 16) & 1u;
    x += 0x7fffu + lsb;
    return (unsigned short)(x >> 16);
}
__device__ __forceinline__ float sigm(float z) {
    return 1.f / (1.f + __expf(-z));
}
// fast gate nonlinearities (v_exp + v_rcp, saturation-safe at +-inf)
__device__ __forceinline__ float rcpf(float x) { return __builtin_amdgcn_rcpf(x); }
__device__ __forceinline__ float sigm_f(float z) { return rcpf(1.f + __expf(-z)); }
__device__ __forceinline__ float tanh_f(float z) { return 1.f - 2.f * rcpf(1.f + __expf(2.f * z)); }

// Agent-coherent 16B load (bypasses non-coherent local caches).
// Caller must s_waitcnt vmcnt(0) + sched_barrier(0) before consuming.
__device__ __forceinline__ bf16x8 ldg_sc(const unsigned short* p) {
    bf16x8 r;
    asm volatile("global_load_dwordx4 %0, %1, off sc1"
                 : "=v"(r) : "v"(p) : "memory");
    return r;
}

// in-quad 4x4 transpose: lane q of each 4-lane quad holds row a[0..3]=M[q][:];
// after: a[g] = M[g][q].
__device__ __forceinline__ void tr4(float a[4], int q) {
    float u0 = (q & 1) ? a[0] : a[1];
    float u1 = (q & 1) ? a[2] : a[3];
    float v0 = __shfl_xor(u0, 1);
    float v1 = __shfl_xor(u1, 1);
    if (q & 1) { a[0] = v0; a[2] = v1; } else { a[1] = v0; a[3] = v1; }
    float w0 = (q & 2) ? a[0] : a[2];
    float w1 = (q & 2) ? a[1] : a[3];
    float s0 = __shfl_xor(w0, 2);
    float s1 = __shfl_xor(w1, 2);
    if (q & 2) { a[0] = s0; a[1] = s1; } else { a[2] = s0; a[3] = s1; }
}

// ---------------------------------------------------------------------------
// prep_M: M = WQ1^T @ WK1  (256x256), bf16 in MFMA B-fragment order.
// ---------------------------------------------------------------------------
__global__ void __launch_bounds__(256) prep_M(const float* __restrict__ WQ1,
                                              const float* __restrict__ WK1,
                                              unsigned short* __restrict__ M_pk) {
    __shared__ unsigned short As[256][32];
    __shared__ unsigned short Bs[256][32];
    int bx = blockIdx.x;
    int e0 = (bx >> 3) << 5;
    int f0 = (bx & 7) << 5;
    int tid = threadIdx.x;
    int col = tid & 31, rr = tid >> 5;
    for (int rep = 0; rep < 32; ++rep) {
        int d = rep * 8 + rr;
        As[d][col] = f2bf(WQ1[d * 256 + e0 + col]);
        Bs[d][col] = f2bf(WK1[d * 256 + f0 + col]);
    }
    __syncthreads();
    int el = tid & 31;
    int fl0 = tid >> 5;
    for (int i = 0; i < 4; ++i) {
        int fl = fl0 + 8 * i;
        float acc = 0.f;
        for (int d = 0; d < 256; ++d)
            acc += bf2f(As[d][el]) * bf2f(Bs[d][fl]);
        int e = e0 + el, f = f0 + fl;
        int kb = e >> 5, r = (e >> 3) & 3, j = e & 7;
        int nb = f >> 4;
        int lane = (r << 4) | (f & 15);
        M_pk[(((nb * 8 + kb) * 64) + lane) * 8 + j] = f2bf(acc);
    }
}

// ---------------------------------------------------------------------------
// pack_rec: all-gates-per-wave fragment streams.
// A (chunks 0..511):  chunk = wa*8+kb, wa=wave-slot (d_w=wa*4), col=dloc*4+gate
//                     -> Whh1[gate*256 + wa*4+dloc][kb*32 + kh*8 + j]
// B (chunks 512..1535): chunk = 512 + wb*16 + kk; kk<8 -> Wih2, kk>=8 -> Whh2
// Block 384 zeroes the flag array (64 rows x 128 slots).
// ---------------------------------------------------------------------------
__global__ void __launch_bounds__(256) pack_rec(const float* __restrict__ Whh1,
                                                const float* __restrict__ Wih2,
                                                const float* __restrict__ Whh2,
                                                unsigned short* __restrict__ Wpk_hi,
                                                unsigned short* __restrict__ Wpk_lo,
                                                int* __restrict__ flags) {
    if (blockIdx.x == 384) {
        for (int i = threadIdx.x; i < 8192; i += 256) flags[i] = 0;
        return;
    }
    int ct = blockIdx.x * 256 + threadIdx.x;   // 98304 threads = 1536 chunks x 64
    int chunk = ct >> 6, lane = ct & 63;
    int col = lane & 15, kh = lane >> 4;
    int gate = col & 3, dloc = col >> 2;
    const float* src;
    int grow, k0;
    if (chunk < 512) {
        int wa = chunk >> 3, kb = chunk & 7;
        grow = gate * 256 + wa * 4 + dloc;
        k0 = kb * 32 + kh * 8;
        src = Whh1;
    } else {
        int cc = chunk - 512;
        int wb = cc >> 4, kk = cc & 15;
        grow = gate * 256 + wb * 4 + dloc;
        k0 = (kk & 7) * 32 + kh * 8;
        src = (kk >= 8) ? Whh2 : Wih2;
    }
    const float* sp = src + (size_t)grow * 256 + k0;
    bf16x8 hi, lo;
    for (int j = 0; j < 8; ++j) {
        float v = sp[j];
        unsigned short h = f2bf(v);
        hi[j] = (short)h;
        lo[j] = (short)f2bf(v - bf2f(h));
    }
    size_t o = (size_t)ct * 8;
    *reinterpret_cast<bf16x8*>(Wpk_hi + o) = hi;
    *reinterpret_cast<bf16x8*>(Wpk_lo + o) = lo;
}

// ---------------------------------------------------------------------------
// pack_w1: Wih1 -> bf16 hi/lo fragment stream. Block 128: alpha cumprod.
// ---------------------------------------------------------------------------
__global__ void __launch_bounds__(256) pack_w1(const float* __restrict__ Wih1,
                                               unsigned short* __restrict__ W1h,
                                               unsigned short* __restrict__ W1l,
                                               const float* __restrict__ betas,
                                               const int* __restrict__ dift,
                                               float* __restrict__ alpha) {
    if (blockIdx.x == 128) {
        int tid = threadIdx.x;
        if (tid < 32) {
            int tb = dift[tid];
            float p = 1.f;
            for (int i = 0; i <= tb; ++i) p *= (1.f - betas[i]);
            alpha[tid] = p;
        }
        return;
    }
    int c = blockIdx.x * 256 + threadIdx.x;
    int nt = c >> 9;
    int r = c & 511;
    int kb = r >> 6;
    int lane = r & 63;
    int grow = nt * 16 + (lane & 15);
    int k0 = kb * 32 + (lane >> 4) * 8;
    const float* sp = Wih1 + (size_t)grow * 256 + k0;
    bf16x8 hi, lo;
    for (int j = 0; j < 8; ++j) {
        float v = sp[j];
        unsigned short h = f2bf(v);
        hi[j] = (short)h;
        lo[j] = (short)f2bf(v - bf2f(h));
    }
    size_t o = (size_t)c * 8;
    *reinterpret_cast<bf16x8*>(W1h + o) = hi;
    *reinterpret_cast<bf16x8*>(W1l + o) = lo;
}

// ---------------------------------------------------------------------------
// attn_bags (unchanged, verified)
// ---------------------------------------------------------------------------
__global__ void __launch_bounds__(256) attn_bags(
    const int* __restrict__ seqs, const float* __restrict__ tstep,
    const float* __restrict__ cmask, const float* __restrict__ emb,
    const float* __restrict__ decay, const float* __restrict__ initial,
    const unsigned short* __restrict__ M_pk, float* __restrict__ vv) {
    __shared__ __align__(16) unsigned short x_bf[32 * 256];
    __shared__ __align__(16) unsigned short t1_bf[32 * 256];
    __shared__ float dp_f[32 * 33];
    __shared__ float gate_sh[32];
    __shared__ float cm_sh[32];
    __shared__ int tok_sh[32];
    __shared__ float w_sh[32];

    int bag = blockIdx.x;
    int tid = threadIdx.x;

    if (tid < 32) {
        int tok = seqs[bag * 32 + tid];
        tok_sh[tid] = tok;
        float cm = cmask[bag * 32 + tid];
        cm_sh[tid] = cm;
        float tt = tstep[bag];
        float g = sigm(decay[tok] * tt + initial[tok]);
        g *= (cm - 1e20f) / (-1e20f);
        gate_sh[tid] = g;
    }
    __syncthreads();

    for (int it = 0; it < 8; ++it) {
        int fidx = it * 256 + tid;
        int c = fidx >> 6;
        int f4 = fidx & 63;
        const float4* src = reinterpret_cast<const float4*>(emb + (size_t)tok_sh[c] * 256) + f4;
        float4 vx = *src;
        int colx = f4 * 4;
        int eidx = c * 256 + (colx ^ ((c & 7) << 3));
        ushort4 w;
        w.x = f2bf(vx.x); w.y = f2bf(vx.y); w.z = f2bf(vx.z); w.w = f2bf(vx.w);
        *reinterpret_cast<ushort4*>(&x_bf[eidx]) = w;
    }
    __syncthreads();

    int wv = tid >> 6;
    int lane = tid & 63;
    int lr = lane & 15;
    int lk = lane >> 4;

    f32x4 acc[2][4];
    for (int a = 0; a < 2; ++a)
        for (int n = 0; n < 4; ++n) acc[a][n] = (f32x4){0.f, 0.f, 0.f, 0.f};
    for (int kb = 0; kb < 8; ++kb) {
        bf16x8 afr[2];
        for (int mb = 0; mb < 2; ++mb) {
            int row = mb * 16 + lr;
            int colx = kb * 32 + lk * 8;
            afr[mb] = *reinterpret_cast<const bf16x8*>(&x_bf[row * 256 + (colx ^ ((row & 7) << 3))]);
        }
        for (int nbi = 0; nbi < 4; ++nbi) {
            int nb = wv * 4 + nbi;
            bf16x8 bfr = *reinterpret_cast<const bf16x8*>(M_pk + (((nb * 8 + kb) * 64) + lane) * 8);
            acc[0][nbi] = __builtin_amdgcn_mfma_f32_16x16x32_bf16(afr[0], bfr, acc[0][nbi], 0, 0, 0);
            acc[1][nbi] = __builtin_amdgcn_mfma_f32_16x16x32_bf16(afr[1], bfr, acc[1][nbi], 0, 0, 0);
        }
    }
    for (int mb = 0; mb < 2; ++mb)
        for (int nbi = 0; nbi < 4; ++nbi)
            for (int r = 0; r < 4; ++r) {
                int row = mb * 16 + lk * 4 + r;
                int colx = wv * 64 + nbi * 16 + lr;
                t1_bf[row * 256 + (colx ^ ((row & 7) << 3))] = f2bf(acc[mb][nbi][r]);
            }
    __syncthreads();

    {
        int mb = wv >> 1, nb2 = wv & 1;
        f32x4 dacc = (f32x4){0.f, 0.f, 0.f, 0.f};
        for (int kb = 0; kb < 8; ++kb) {
            int cola = kb * 32 + lk * 8;
            int rowa = mb * 16 + lr;
            bf16x8 afr = *reinterpret_cast<const bf16x8*>(&t1_bf[rowa * 256 + (cola ^ ((rowa & 7) << 3))]);
            int rowb = nb2 * 16 + lr;
            bf16x8 bfr = *reinterpret_cast<const bf16x8*>(&x_bf[rowb * 256 + (cola ^ ((rowb & 7) << 3))]);
            dacc = __builtin_amdgcn_mfma_f32_16x16x32_bf16(afr, bfr, dacc, 0, 0, 0);
        }
        for (int r = 0; r < 4; ++r) {
            int c = mb * 16 + lk * 4 + r;
            int e = nb2 * 16 + lr;
            dp_f[c * 33 + e] = dacc[r];
        }
    }
    __syncthreads();

    if (tid < 32) {
        int c = tid;
        float cmc = cm_sh[c];
        float lg[32];
        float mx = -1e30f;
        for (int e = 0; e < 32; ++e) {
            float l = (dp_f[c * 33 + e] - cmc - cm_sh[e]) * 0.0625f;
            lg[e] = l;
            mx = fmaxf(mx, l);
        }
        float s = 0.f;
        for (int e = 0; e < 32; ++e) { float ex = __expf(lg[e] - mx); lg[e] = ex; s += ex; }
        float inv = 1.f / s;
        for (int e = 0; e < 32; ++e) dp_f[c * 33 + e] = lg[e] * inv;
    }
    __syncthreads();
    if (tid < 32) {
        int e = tid;
        float a2 = 0.f;
        for (int c = 0; c < 32; ++c) a2 += gate_sh[c] * dp_f[c * 33 + e];
        w_sh[e] = a2;
    }
    __syncthreads();

    float accv = 0.f;
    int d = tid;
    for (int e = 0; e < 32; ++e)
        accv += w_sh[e] * bf2f(x_bf[e * 256 + (d ^ ((e & 7) << 3))]);
    vv[(size_t)bag * 256 + d] = accv;
}

// ---------------------------------------------------------------------------
// x1_mfma: X1bf[t][b][d][gate] = bf16( vv @ Wih1^T + lstm_b )
// ---------------------------------------------------------------------------
__global__ void __launch_bounds__(256) x1_mfma(const float* __restrict__ vv,
                                               const unsigned short* __restrict__ W1h,
                                               const unsigned short* __restrict__ W1l,
                                               const float* __restrict__ lstm_b,
                                               unsigned short* __restrict__ X1bf) {
    __shared__ __align__(16) unsigned short xs[32 * 256];
    int blk = blockIdx.x;
    int rb = blk >> 3, gb = blk & 7;
    int tid = threadIdx.x;
    for (int it = 0; it < 8; ++it) {
        int idx = it * 256 + tid;
        int row = idx >> 6, f4 = idx & 63;
        float4 v = *reinterpret_cast<const float4*>(vv + (size_t)(rb * 32 + row) * 256 + f4 * 4);
        ushort4 w;
        w.x = f2bf(v.x); w.y = f2bf(v.y); w.z = f2bf(v.z); w.w = f2bf(v.w);
        *reinterpret_cast<ushort4*>(&xs[row * 256 + ((f4 * 4) ^ ((row & 7) << 3))]) = w;
    }
    __syncthreads();
    int wv = tid >> 6, lane = tid & 63, cl = lane & 15, kh = lane >> 4;
    f32x4 acc[2][2];
    for (int n = 0; n < 2; ++n) {
        int nt = gb * 8 + wv * 2 + n;
        float bz = lstm_b[nt * 16 + cl];
        acc[n][0] = (f32x4){bz, bz, bz, bz};
        acc[n][1] = (f32x4){bz, bz, bz, bz};
    }
    #pragma unroll
    for (int kb = 0; kb < 8; ++kb) {
        int k = kb * 32 + kh * 8;
        bf16x8 a0 = *reinterpret_cast<const bf16x8*>(&xs[cl * 256 + (k ^ ((cl & 7) << 3))]);
        bf16x8 a1 = *reinterpret_cast<const bf16x8*>(&xs[(16 + cl) * 256 + (k ^ (((16 + cl) & 7) << 3))]);
        for (int n = 0; n < 2; ++n) {
            int nt = gb * 8 + wv * 2 + n;
            size_t o = ((size_t)(nt * 8 + kb) * 64 + lane) * 8;
            bf16x8 bh = *reinterpret_cast<const bf16x8*>(W1h + o);
            bf16x8 bl = *reinterpret_cast<const bf16x8*>(W1l + o);
            acc[n][0] = __builtin_amdgcn_mfma_f32_16x16x32_bf16(a0, bh, acc[n][0], 0, 0, 0);
            acc[n][0] = __builtin_amdgcn_mfma_f32_16x16x32_bf16(a0, bl, acc[n][0], 0, 0, 0);
            acc[n][1] = __builtin_amdgcn_mfma_f32_16x16x32_bf16(a1, bh, acc[n][1], 0, 0, 0);
            acc[n][1] = __builtin_amdgcn_mfma_f32_16x16x32_bf16(a1, bl, acc[n][1], 0, 0, 0);
        }
    }
    for (int n = 0; n < 2; ++n) {
        int nt = gb * 8 + wv * 2 + n;
        int g = nt * 16 + cl;
        int dX = g & 255, gt = g >> 8;
        for (int mt = 0; mt < 2; ++mt)
            for (int r = 0; r < 4; ++r) {
                int row = rb * 32 + mt * 16 + kh * 4 + r;
                int b = row >> 6, t = row & 63;
                X1bf[((size_t)t * 32 + b) * 1024 + dX * 4 + gt] = f2bf(acc[n][mt][r]);
            }
    }
}

// ---------------------------------------------------------------------------
// lstm_persist: barrier-free, wave-autonomous. 32 wgs x 256 thr.
// wgs 0..15 (A/LSTM1): 64 wave-slots, each owns d-slice 4 (all 4 gates).
// wgs 16..31 (B/LSTM2): 64 wave-slots, concat-K over [h1[s]; h2[s-1]].
// No LDS, no __syncthreads. Per-wave flags: flags[step*128 + slot(+64 for B)].
// ---------------------------------------------------------------------------
__global__ void __launch_bounds__(256, 1) lstm_persist(
    const unsigned short* __restrict__ Wpk_hi, const unsigned short* __restrict__ Wpk_lo,
    const unsigned short* __restrict__ X1bf, const float* __restrict__ hs_b,
    unsigned short* h1, unsigned short* h2, int* flags) {
    int wg = blockIdx.x, tid = threadIdx.x;
    int wv = tid >> 6, lane = tid & 63;
    int c = lane & 15, grp = lane >> 4;
    int q = c & 3, dloc = c >> 2;
    bool isA = wg < 16;
    int slot = (isA ? wg : (wg - 16)) * 4 + wv;    // 0..63 within role
    int d = slot * 4 + dloc;
    int b0 = grp * 4 + q;                           // gate-stage batch (mt0)

    if (isA) {
        bf16x8 wh[8], wl[8];
        #pragma unroll
        for (int kb = 0; kb < 8; ++kb) {
            size_t o = ((size_t)(slot * 8 + kb) * 64 + lane) * 8;
            wh[kb] = *reinterpret_cast<const bf16x8*>(Wpk_hi + o);
            wl[kb] = *reinterpret_cast<const bf16x8*>(Wpk_lo + o);
        }
        float cst0 = 0.f, cst1 = 0.f;
        for (int p = 0; p < 64; ++p) {
            // step-local X1 (independent of flags) - issue early
            ushort4 x1v0 = *reinterpret_cast<const ushort4*>(
                X1bf + (((size_t)p * 32 + b0) * 256 + d) * 4);
            ushort4 x1v1 = *reinterpret_cast<const ushort4*>(
                X1bf + (((size_t)p * 32 + b0 + 16) * 256 + d) * 4);
            f32x4 acc0 = (f32x4){0.f, 0.f, 0.f, 0.f};
            f32x4 acc1 = acc0;
            if (p > 0) {
                const int* f = flags + (p - 1) * 128;
                while (1) {
                    int v = __hip_atomic_load(f + lane, __ATOMIC_RELAXED, __HIP_MEMORY_SCOPE_AGENT);
                    if (__all(v != 0)) break;
                    __builtin_amdgcn_s_sleep(1);
                }
                __builtin_amdgcn_sched_barrier(0);
                const unsigned short* hB = h1 + (size_t)(p - 1) * 8192;
                bf16x8 a0[8], a1[8];
                #pragma unroll
                for (int kb = 0; kb < 8; ++kb) {
                    a0[kb] = ldg_sc(hB + c * 256 + kb * 32 + grp * 8);
                    a1[kb] = ldg_sc(hB + (16 + c) * 256 + kb * 32 + grp * 8);
                }
                asm volatile("s_waitcnt vmcnt(0)" ::: "memory");
                __builtin_amdgcn_sched_barrier(0);
                #pragma unroll
                for (int kb = 0; kb < 8; ++kb) {
                    acc0 = __builtin_amdgcn_mfma_f32_16x16x32_bf16(a0[kb], wh[kb], acc0, 0, 0, 0);
                    acc0 = __builtin_amdgcn_mfma_f32_16x16x32_bf16(a0[kb], wl[kb], acc0, 0, 0, 0);
                    acc1 = __builtin_amdgcn_mfma_f32_16x16x32_bf16(a1[kb], wh[kb], acc1, 0, 0, 0);
                    acc1 = __builtin_amdgcn_mfma_f32_16x16x32_bf16(a1[kb], wl[kb], acc1, 0, 0, 0);
                }
            }
            float za[4] = {acc0[0], acc0[1], acc0[2], acc0[3]};
            float zb[4] = {acc1[0], acc1[1], acc1[2], acc1[3]};
            tr4(za, q);
            tr4(zb, q);
            float zi = za[0] + bf2f(x1v0.x);
            float zf = za[1] + bf2f(x1v0.y);
            float zg = za[2] + bf2f(x1v0.z);
            float zo = za[3] + bf2f(x1v0.w);
            float cn0 = sigm_f(zf) * cst0 + sigm_f(zi) * tanh_f(zg);
            float hn0 = sigm_f(zo) * tanh_f(cn0);
            cst0 = cn0;
            zi = zb[0] + bf2f(x1v1.x);
            zf = zb[1] + bf2f(x1v1.y);
            zg = zb[2] + bf2f(x1v1.z);
            zo = zb[3] + bf2f(x1v1.w);
            float cn1 = sigm_f(zf) * cst1 + sigm_f(zi) * tanh_f(zg);
            float hn1 = sigm_f(zo) * tanh_f(cn1);
            cst1 = cn1;
            // pack (d, d+1) pairs across lanes c and c^4, dword agent store
            unsigned int pk0 = f2bf(hn0), pk1 = f2bf(hn1);
            unsigned int pr0 = (unsigned int)__shfl_xor((int)pk0, 4);
            unsigned int pr1 = (unsigned int)__shfl_xor((int)pk1, 4);
            if ((c & 4) == 0) {
                __hip_atomic_store((unsigned int*)h1 + ((((size_t)p * 32 + b0) * 256 + d) >> 1),
                                   pk0 | (pr0 << 16), __ATOMIC_RELAXED, __HIP_MEMORY_SCOPE_AGENT);
                __hip_atomic_store((unsigned int*)h1 + ((((size_t)p * 32 + b0 + 16) * 256 + d) >> 1),
                                   pk1 | (pr1 << 16), __ATOMIC_RELAXED, __HIP_MEMORY_SCOPE_AGENT);
            }
            asm volatile("s_waitcnt vmcnt(0)" ::: "memory");
            if (lane == 0)
                __hip_atomic_store(flags + p * 128 + slot, 1,
                                   __ATOMIC_RELAXED, __HIP_MEMORY_SCOPE_AGENT);
        }
    } else {
        bf16x8 wh[16], wl[16];
        #pragma unroll
        for (int kk = 0; kk < 16; ++kk) {
            size_t o = ((size_t)((512 + slot * 16 + kk)) * 64 + lane) * 8;
            wh[kk] = *reinterpret_cast<const bf16x8*>(Wpk_hi + o);
            wl[kk] = *reinterpret_cast<const bf16x8*>(Wpk_lo + o);
        }
        float bias[4];
        #pragma unroll
        for (int g = 0; g < 4; ++g) bias[g] = hs_b[g * 256 + d];
        float cst0 = 0.f, cst1 = 0.f;
        for (int s = 0; s < 64; ++s) {
            {   // poll A row s (+ B row s-1 when s>0)
                const int* fA = flags + s * 128;
                const int* fB = flags + (s - 1) * 128 + 64;
                while (1) {
                    int va = __hip_atomic_load(fA + lane, __ATOMIC_RELAXED, __HIP_MEMORY_SCOPE_AGENT);
                    int ok = (va != 0);
                    if (s > 0) {
                        int vb = __hip_atomic_load(fB + lane, __ATOMIC_RELAXED, __HIP_MEMORY_SCOPE_AGENT);
                        ok = ok && (vb != 0);
                    }
                    if (__all(ok)) break;
                    __builtin_amdgcn_s_sleep(1);
                }
                __builtin_amdgcn_sched_barrier(0);
            }
            f32x4 acc0 = (f32x4){0.f, 0.f, 0.f, 0.f};
            f32x4 acc1 = acc0;
            {
                const unsigned short* h1s = h1 + (size_t)s * 8192;
                bf16x8 a0[16], a1[16];
                #pragma unroll
                for (int kk = 0; kk < 8; ++kk) {
                    a0[kk] = ldg_sc(h1s + c * 256 + kk * 32 + grp * 8);
                    a1[kk] = ldg_sc(h1s + (16 + c) * 256 + kk * 32 + grp * 8);
                }
                if (s > 0) {
                    const unsigned short* h2s = h2 + (size_t)(s - 1) * 8192;
                    #pragma unroll
                    for (int kk = 8; kk < 16; ++kk) {
                        a0[kk] = ldg_sc(h2s + c * 256 + (kk - 8) * 32 + grp * 8);
                        a1[kk] = ldg_sc(h2s + (16 + c) * 256 + (kk - 8) * 32 + grp * 8);
                    }
                }
                asm volatile("s_waitcnt vmcnt(0)" ::: "memory");
                __builtin_amdgcn_sched_barrier(0);
                #pragma unroll
                for (int kk = 0; kk < 8; ++kk) {
                    acc0 = __builtin_amdgcn_mfma_f32_16x16x32_bf16(a0[kk], wh[kk], acc0, 0, 0, 0);
                    acc0 = __builtin_amdgcn_mfma_f32_16x16x32_bf16(a0[kk], wl[kk], acc0, 0, 0, 0);
                    acc1 = __builtin_amdgcn_mfma_f32_16x16x32_bf16(a1[kk], wh[kk], acc1, 0, 0, 0);
                    acc1 = __builtin_amdgcn_mfma_f32_16x16x32_bf16(a1[kk], wl[kk], acc1, 0, 0, 0);
                }
                if (s > 0) {
                    #pragma unroll
                    for (int kk = 8; kk < 16; ++kk) {
                        acc0 = __builtin_amdgcn_mfma_f32_16x16x32_bf16(a0[kk], wh[kk], acc0, 0, 0, 0);
                        acc0 = __builtin_amdgcn_mfma_f32_16x16x32_bf16(a0[kk], wl[kk], acc0, 0, 0, 0);
                        acc1 = __builtin_amdgcn_mfma_f32_16x16x32_bf16(a1[kk], wh[kk], acc1, 0, 0, 0);
                        acc1 = __builtin_amdgcn_mfma_f32_16x16x32_bf16(a1[kk], wl[kk], acc1, 0, 0, 0);
                    }
                }
            }
            float za[4] = {acc0[0], acc0[1], acc0[2], acc0[3]};
            float zb[4] = {acc1[0], acc1[1], acc1[2], acc1[3]};
            tr4(za, q);
            tr4(zb, q);
            float cn0 = sigm_f(za[1] + bias[1]) * cst0 +
                        sigm_f(za[0] + bias[0]) * tanh_f(za[2] + bias[2]);
            float hn0 = sigm_f(za[3] + bias[3]) * tanh_f(cn0);
            cst0 = cn0;
            float cn1 = sigm_f(zb[1] + bias[1]) * cst1 +
                        sigm_f(zb[0] + bias[0]) * tanh_f(zb[2] + bias[2]);
            float hn1 = sigm_f(zb[3] + bias[3]) * tanh_f(cn1);
            cst1 = cn1;
            unsigned int pk0 = f2bf(hn0), pk1 = f2bf(hn1);
            unsigned int pr0 = (unsigned int)__shfl_xor((int)pk0, 4);
            unsigned int pr1 = (unsigned int)__shfl_xor((int)pk1, 4);
            if ((c & 4) == 0) {
                __hip_atomic_store((unsigned int*)h2 + ((((size_t)s * 32 + b0) * 256 + d) >> 1),
                                   pk0 | (pr0 << 16), __ATOMIC_RELAXED, __HIP_MEMORY_SCOPE_AGENT);
                __hip_atomic_store((unsigned int*)h2 + ((((size_t)s * 32 + b0 + 16) * 256 + d) >> 1),
                                   pk1 | (pr1 << 16), __ATOMIC_RELAXED, __HIP_MEMORY_SCOPE_AGENT);
            }
            asm volatile("s_waitcnt vmcnt(0)" ::: "memory");
            if (lane == 0)
                __hip_atomic_store(flags + s * 128 + 64 + slot, 1,
                                   __ATOMIC_RELAXED, __HIP_MEMORY_SCOPE_AGENT);
        }
    }
}

// ---------------------------------------------------------------------------
// tail_k: per batch, only row v* = lengths[b]-1 matters.
// ---------------------------------------------------------------------------
__global__ void __launch_bounds__(256) tail_k(
    const int* __restrict__ lengths,
    const unsigned short* __restrict__ h1, const unsigned short* __restrict__ h2,
    const float* __restrict__ whk_W, const float* __restrict__ whk_b,
    const float* __restrict__ w1_W, const float* __restrict__ w1_b,
    const float* __restrict__ w2_W, const float* __restrict__ w2_b,
    const float* __restrict__ fuse_W, const float* __restrict__ fuse_b,
    const float* __restrict__ lab_W, const float* __restrict__ lab_b,
    const float* __restrict__ Wdiff, const float* __restrict__ alpha,
    const float* __restrict__ noise, float* __restrict__ out) {
    __shared__ float ek[256], tv[256], hs[256], whp[256], a1s[64];
    __shared__ float noisy_s[256], fin[512], fused_s[256], attn_s[2];
    int b = blockIdx.x, tid = threadIdx.x;
    int vstar = lengths[b] - 1;
    {
        ek[tid] = bf2f(h1[(size_t)b * 256 + tid]);
        tv[tid] = bf2f(h1[((size_t)vstar * 32 + b) * 256 + tid]);
        if (vstar > 0)
            hs[tid] = bf2f(h2[((size_t)(vstar - 1) * 32 + b) * 256 + tid]);
    }
    __syncthreads();

    float aligned;
    if (vstar > 0) {
        float acc = whk_b[tid];
        const float4* wr4 = reinterpret_cast<const float4*>(whk_W + (size_t)tid * 256);
        #pragma unroll 8
        for (int k4 = 0; k4 < 64; ++k4) {
            float4 w = wr4[k4];
            acc += w.x * hs[k4 * 4] + w.y * hs[k4 * 4 + 1] + w.z * hs[k4 * 4 + 2] + w.w * hs[k4 * 4 + 3];
        }
        whp[tid] = acc;
        __syncthreads();
        if (tid < 64) {
            float a2 = w1_b[tid];
            const float4* wr14 = reinterpret_cast<const float4*>(w1_W + (size_t)tid * 512);
            #pragma unroll 8
            for (int k4 = 0; k4 < 64; ++k4) {
                float4 w = wr14[k4];
                a2 += w.x * ek[k4 * 4] + w.y * ek[k4 * 4 + 1] + w.z * ek[k4 * 4 + 2] + w.w * ek[k4 * 4 + 3];
            }
            #pragma unroll 8
            for (int k4 = 0; k4 < 64; ++k4) {
                float4 w = wr14[64 + k4];
                a2 += w.x * whp[k4 * 4] + w.y * whp[k4 * 4 + 1] + w.z * whp[k4 * 4 + 2] + w.w * whp[k4 * 4 + 3];
            }
            a1s[tid] = tanhf(a2);
        }
        __syncthreads();
        if (tid < 2) {
            float a3 = w2_b[tid];
            const float* wr2 = w2_W + tid * 64;
            for (int k = 0; k < 64; ++k) a3 += wr2[k] * a1s[k];
            attn_s[tid] = a3;
        }
        __syncthreads();
        float m = fmaxf(attn_s[0], attn_s[1]);
        float e0 = __expf(attn_s[0] - m), e1 = __expf(attn_s[1] - m);
        float inv = 1.f / (e0 + e1);
        aligned = ek[tid] * (e0 * inv) + whp[tid] * (e1 * inv);
    } else {
        aligned = ek[tid];
    }

    float al = alpha[b];
    float sa = sqrtf(al), sb = sqrtf(1.f - al);
    float nz = noise[((size_t)b * 64 + vstar) * 256 + tid];
    noisy_s[tid] = aligned * sa + nz * sb;
    __syncthreads();
    float pn = 0.f;
    for (int k = 0; k < 256; ++k) pn += noisy_s[k] * Wdiff[(size_t)k * 256 + tid];
    float gen = aligned + nz - pn;
    fin[tid] = tv[tid];
    fin[256 + tid] = gen;
    __syncthreads();
    float fu = fuse_b[tid];
    const float4* fw4 = reinterpret_cast<const float4*>(fuse_W + (size_t)tid * 512);
    #pragma unroll 8
    for (int k4 = 0; k4 < 128; ++k4) {
        float4 w = fw4[k4];
        fu += w.x * fin[k4 * 4] + w.y * fin[k4 * 4 + 1] + w.z * fin[k4 * 4 + 2] + w.w * fin[k4 * 4 + 3];
    }
    fused_s[tid] = fu;
    __syncthreads();
    if (tid < 2) {
        float o = lab_b[tid];
        const float* lw = lab_W + tid * 256;
        for (int k = 0; k < 256; ++k) o += lw[k] * fused_s[k];
        out[b * 2 + tid] = o;
    }
}

// ---------------------------------------------------------------------------
extern "C" void kernel_launch(void* const* d_in, const int* in_sizes, int n_in,
                              void* d_out, int out_size, void* d_ws, size_t ws_size,
                              hipStream_t stream) {
    const int*   seqs    = (const int*)  d_in[0];
    const int*   lengths = (const int*)  d_in[2];
    const float* tstep   = (const float*)d_in[3];
    const float* cmask   = (const float*)d_in[4];
    const float* emb     = (const float*)d_in[5];
    const float* WQ1     = (const float*)d_in[6];
    const float* WK1     = (const float*)d_in[7];
    const float* decay   = (const float*)d_in[8];
    const float* initial = (const float*)d_in[9];
    const float* Wih1    = (const float*)d_in[10];
    const float* Whh1    = (const float*)d_in[11];
    const float* lstm_b  = (const float*)d_in[12];
    const float* Wih2    = (const float*)d_in[13];
    const float* Whh2    = (const float*)d_in[14];
    const float* hs_b    = (const float*)d_in[15];
    const float* whk_W   = (const float*)d_in[16];
    const float* whk_b   = (const float*)d_in[17];
    const float* w1_W    = (const float*)d_in[18];
    const float* w1_b    = (const float*)d_in[19];
    const float* w2_W    = (const float*)d_in[20];
    const float* w2_b    = (const float*)d_in[21];
    const float* fuse_W  = (const float*)d_in[22];
    const float* fuse_b  = (const float*)d_in[23];
    const float* lab_W   = (const float*)d_in[24];
    const float* lab_b   = (const float*)d_in[25];
    const float* betas   = (const float*)d_in[26];
    const float* Wdiff   = (const float*)d_in[27];
    const int*   dift    = (const int*)  d_in[28];
    const float* noise   = (const float*)d_in[29];
    float* out = (float*)d_out;

    float* ws = (float*)d_ws;
    size_t off = 0;
    auto alloc = [&](size_t nfloats) { size_t r = off; off += (nfloats + 63) & ~(size_t)63; return r; };
    unsigned short* M_pk   = (unsigned short*)(ws + alloc(32768));
    float*          alpha  = ws + alloc(64);
    int*            flags  = (int*)(ws + alloc(8192));                // 64 rows x 128 slots
    float*          vv     = ws + alloc(524288);
    unsigned short* X1bf   = (unsigned short*)(ws + alloc(1048576));  // 64*32*1024 u16
    unsigned short* h1     = (unsigned short*)(ws + alloc(262144));   // 64*32*256 u16 (1 MB)
    unsigned short* h2     = (unsigned short*)(ws + alloc(262144));
    unsigned short* Wpk_hi = (unsigned short*)(ws + alloc(393216));   // 1536 chunks * 512 u16
    unsigned short* Wpk_lo = (unsigned short*)(ws + alloc(393216));
    unsigned short* W1h    = (unsigned short*)(ws + alloc(131072));
    unsigned short* W1l    = (unsigned short*)(ws + alloc(131072));

    prep_M<<<64, 256, 0, stream>>>(WQ1, WK1, M_pk);
    pack_rec<<<385, 256, 0, stream>>>(Whh1, Wih2, Whh2, Wpk_hi, Wpk_lo, flags);
    pack_w1<<<129, 256, 0, stream>>>(Wih1, W1h, W1l, betas, dift, alpha);
    attn_bags<<<2048, 256, 0, stream>>>(seqs, tstep, cmask, emb, decay, initial, M_pk, vv);
    x1_mfma<<<512, 256, 0, stream>>>(vv, W1h, W1l, lstm_b, X1bf);
    lstm_persist<<<32, 256, 0, stream>>>(Wpk_hi, Wpk_lo, X1bf, hs_b, h1, h2, flags);
    tail_k<<<32, 256, 0, stream>>>(lengths, h1, h2, whk_W, whk_b,
                                   w1_W, w1_b, w2_W, w2_b, fuse_W, fuse_b,
                                   lab_W, lab_b, Wdiff, alpha, noise, out);
}